// Round 8
// baseline (2525.469 us; speedup 1.0000x reference)
//
#include <hip/hip_runtime.h>
#include <hip/hip_bf16.h>
#include <math.h>
#include <stdint.h>

#define BB 32
#define TT 512
#define II 512
#define HH 512
#define G4 (4 * HH)      // 2048
#define MM (TT * BB)     // 16384 rows of gx per direction
#define BH (BB * HH)     // 16384
#define WGD 16           // workgroups per direction (4 waves, 2 col-groups/wave)

typedef __hip_bfloat16 bf16;
typedef __attribute__((ext_vector_type(8))) short short8;   // 8 bf16 = 4 VGPRs
typedef __attribute__((ext_vector_type(4))) float f32x4;    // MFMA accumulator
typedef __attribute__((ext_vector_type(4))) unsigned u32x4; // for asm loads

__device__ __forceinline__ float bf2f(bf16 v) { return __bfloat162float(v); }
__device__ __forceinline__ bf16  f2bf(float v) { return __float2bfloat16(v); }
__device__ __forceinline__ short f2bs(float x) { bf16 v = f2bf(x); return *reinterpret_cast<short*>(&v); }
__device__ __forceinline__ float bs2f(short s) {
    unsigned u = ((unsigned)(unsigned short)s) << 16;
    return __uint_as_float(u);
}
__device__ __forceinline__ short8 pk8(float4 u, float4 v) {
    short8 t;
    t[0] = f2bs(u.x); t[1] = f2bs(u.y); t[2] = f2bs(u.z); t[3] = f2bs(u.w);
    t[4] = f2bs(v.x); t[5] = f2bs(v.y); t[6] = f2bs(v.z); t[7] = f2bs(v.w);
    return t;
}

// gx gate-planar swizzle: [dl][t][g][cg 0..127][b*4 + jj] bf16
#define GX1 ((size_t)TT * 4 * 128 * 128)   // elements per direction (= MM*G4)

// ---------------------------------------------------------------------------
// Phase 1: input projection GEMM via MFMA (bf16 in / fp32 acc). Unchanged.
// ---------------------------------------------------------------------------
__global__ __launch_bounds__(256) void proj_mfma_kernel(
    const float* __restrict__ x,
    const float* __restrict__ w_f, const float* __restrict__ w_r,
    const float* __restrict__ bi_f, const float* __restrict__ bh_f,
    const float* __restrict__ bi_r, const float* __restrict__ bh_r,
    bf16* __restrict__ gx, int dir0)
{
    const int dl = blockIdx.z, dir = dir0 + dl;
    const int m0 = blockIdx.x * 64;
    const int n0 = blockIdx.y * 128;
    const float* __restrict__ w  = dir ? w_r  : w_f;
    const float* __restrict__ bi = dir ? bi_r : bi_f;
    const float* __restrict__ bh = dir ? bh_r : bh_f;

    __shared__ __align__(16) char smem[17408];
    bf16 (*As)[40]  = (bf16(*)[40])smem;            // 64 x (32+8 pad)
    bf16 (*Bs)[40]  = (bf16(*)[40])(smem + 5120);   // 128 x (32+8 pad)
    bf16 (*Cs)[136] = (bf16(*)[136])smem;           // 64 x 136 (reuses smem)

    const int tid = threadIdx.x;
    const int wv = tid >> 6, l = tid & 63;
    const int nl = l & 15, ko = (l >> 4) * 8;

    const int a_r = tid >> 2, a_s = tid & 3;
    const float* a_src = x + ((size_t)((m0 + a_r) & 31) * TT + (size_t)((m0 + a_r) >> 5)) * II + a_s * 8;
    const int b_r = tid >> 1, b_h = tid & 1;
    const float* b_src = w + (size_t)(n0 + b_r) * II + b_h * 16;

    f32x4 acc[8];
#pragma unroll
    for (int j = 0; j < 8; ++j) acc[j] = (f32x4){0.f, 0.f, 0.f, 0.f};

    float bias[8];
#pragma unroll
    for (int j = 0; j < 8; ++j) {
        const int n = n0 + j * 16 + nl;
        bias[j] = bi[n] + bh[n];
    }

    for (int k0 = 0; k0 < II; k0 += 32) {
        const float4 av0 = *(const float4*)(a_src + k0);
        const float4 av1 = *(const float4*)(a_src + k0 + 4);
        const float4 bv0 = *(const float4*)(b_src + k0);
        const float4 bv1 = *(const float4*)(b_src + k0 + 4);
        const float4 bv2 = *(const float4*)(b_src + k0 + 8);
        const float4 bv3 = *(const float4*)(b_src + k0 + 12);
        __syncthreads();   // previous tile fully consumed
        *(short8*)&As[a_r][a_s * 8] = pk8(av0, av1);
        *(short8*)&Bs[b_r][b_h * 16]     = pk8(bv0, bv1);
        *(short8*)&Bs[b_r][b_h * 16 + 8] = pk8(bv2, bv3);
        __syncthreads();
        const short8 a = *(const short8*)&As[wv * 16 + nl][ko];
#pragma unroll
        for (int j = 0; j < 8; ++j) {
            const short8 b = *(const short8*)&Bs[j * 16 + nl][ko];
            acc[j] = __builtin_amdgcn_mfma_f32_16x16x32_bf16(a, b, acc[j], 0, 0, 0);
        }
    }

    __syncthreads();
    const int row0 = (l >> 4) * 4;
#pragma unroll
    for (int j = 0; j < 8; ++j)
#pragma unroll
        for (int r = 0; r < 4; ++r)
            Cs[wv * 16 + row0 + r][j * 16 + nl] = f2bf(acc[j][r] + bias[j]);
    __syncthreads();

    bf16* gxd = gx + (size_t)dl * GX1;
    const int g   = n0 >> 9;
    const int cgb = (n0 & 511) >> 2;
    const int t_base = blockIdx.x * 2;
#pragma unroll
    for (int i = 0; i < 4; ++i) {
        const int c = i * 256 + tid;
        const int tl = c >> 9, cgl = (c >> 4) & 31, u = c & 15;
        const int r0 = tl * 32 + 2 * u;
        const uint2 lo = *(const uint2*)&Cs[r0][cgl * 4];
        const uint2 hi = *(const uint2*)&Cs[r0 + 1][cgl * 4];
        uint4 ov; ov.x = lo.x; ov.y = lo.y; ov.z = hi.x; ov.w = hi.y;
        *(uint4*)(gxd + ((((size_t)(t_base + tl) * 4 + g) * 128 + cgb + cgl) * 128 + u * 8)) = ov;
    }
}

// ---------------------------------------------------------------------------
// Shared per-direction cell step: MFMA (h.W^T) + gate math for ONE col-group.
// ---------------------------------------------------------------------------
__device__ __forceinline__ void cell_step(
    const bf16 (*__restrict__ h_s)[520], const short8* __restrict__ bfrag,
    float (*__restrict__ exw)[36],            // this wave's ex slice [16][36]
    const unsigned* __restrict__ gw,
    int nl, int ko, int l, int mC, int jjA,
    float& cs0, float& cs1, float& hv0, float& hv1)
{
    f32x4 acc0 = {0.f, 0.f, 0.f, 0.f};
    f32x4 acc1 = {0.f, 0.f, 0.f, 0.f};
#pragma unroll
    for (int half = 0; half < 2; ++half) {
        short8 a0[8], a1[8];
#pragma unroll
        for (int k = 0; k < 8; ++k) {
            const int ks = half * 8 + k;
            a0[k] = *(const short8*)&h_s[nl][ks * 32 + ko];
            a1[k] = *(const short8*)&h_s[nl + 16][ks * 32 + ko];
        }
#pragma unroll
        for (int k = 0; k < 8; ++k) {
            acc0 = __builtin_amdgcn_mfma_f32_16x16x32_bf16(a0[k], bfrag[half * 8 + k], acc0, 0, 0, 0);
            acc1 = __builtin_amdgcn_mfma_f32_16x16x32_bf16(a1[k], bfrag[half * 8 + k], acc1, 0, 0, 0);
        }
    }
    const int row0 = (l >> 4) * 4;
    *(f32x4*)&exw[nl][row0]      = acc0;
    *(f32x4*)&exw[nl][16 + row0] = acc1;

#pragma unroll
    for (int c = 0; c < 2; ++c) {
        const int jc = jjA + c;
        const int sh = 16 * c;
        float q0 = exw[0 * 4 + jc][mC] + bs2f((short)(gw[0] >> sh));
        float q1 = exw[1 * 4 + jc][mC] + bs2f((short)(gw[1] >> sh));
        float q2 = exw[2 * 4 + jc][mC] + bs2f((short)(gw[2] >> sh));
        float q3 = exw[3 * 4 + jc][mC] + bs2f((short)(gw[3] >> sh));
        q0 = fminf(fmaxf(q0, -30.f), 30.f);
        q1 = fminf(fmaxf(q1, -30.f), 30.f);
        q2 = fminf(fmaxf(q2, -30.f), 30.f);
        q3 = fminf(fmaxf(q3, -30.f), 30.f);
        const float ig = 1.f / (1.f + __expf(-q0));
        const float fg = 1.f / (1.f + __expf(-q1));
        const float te = __expf(2.f * q2);
        const float gg = (te - 1.f) / (te + 1.f);
        const float og = 1.f / (1.f + __expf(-q3));
        float cs = (c == 0) ? cs0 : cs1;
        cs = fg * cs + ig * gg;
        const float csc = fminf(fmaxf(cs, -15.f), 15.f);
        const float t2 = __expf(2.f * csc);
        const float th = (t2 - 1.f) / (t2 + 1.f);
        const float h = og * th;
        if (c == 0) { cs0 = cs; hv0 = h; } else { cs1 = cs; hv1 = h; }
    }
}

// ---------------------------------------------------------------------------
// Phase 2: MFMA recurrence. Round-13 = round-6 structure (flag-store arrival,
// wave-0 parallel poll) with HALF the participants:
//  - 16 WGs/dir x 4 waves; each wave owns TWO col-groups (2x bfrag in regs,
//    two sequential cell_steps; +~0.2us serial compute).
//  - barrier width 16 flags; publish WG count, restage MALL traffic, and the
//    straggler pool all halve. Single-variable test of participant count.
// ---------------------------------------------------------------------------
__global__ __launch_bounds__(256, 1) void lstm_rec_kernel(
    const bf16* __restrict__ gx,
    const float* __restrict__ h0, const float* __restrict__ c0,
    const float* __restrict__ whh_f, const float* __restrict__ whh_r,
    float* __restrict__ dout,
    bf16* __restrict__ h_buf,          // [ndir][2 slots][BH]
    unsigned int* __restrict__ bars,   // [ndir][16 flags x 32 uints (128B)]
    int dir0)
{
    const int dl  = blockIdx.x >> 4;
    const int wgl = blockIdx.x & 15;
    const int dir = dir0 + dl;
    const int tid = threadIdx.x;
    const int wv  = tid >> 6;            // wave 0..3
    const int l   = tid & 63;            // lane
    const int cgA = wgl * 8 + wv * 2;    // first col-group
    const int cgB = cgA + 1;             // second col-group
    const int j0A = cgA * 4, j0B = cgB * 4;
    const float* __restrict__ whh = dir ? whh_r : whh_f;
    unsigned int* barsd = bars + (size_t)dl * 512;

    __shared__ __align__(16) bf16 h_s[32][520];      // staged h, +8 pad
    __shared__ __align__(16) float ex[4][2][16][36]; // per-wave x per-cg exchange

    const int nl = l & 15;                // packed col index = gate*4 + jj
    const int g  = nl >> 2, jj = nl & 3;
    const int ko = (l >> 4) * 8;          // k-octet within a K=32 MFMA step

    // ---- B fragments (w_hh) for BOTH col-groups resident in registers ----
    short8 bfA[16], bfB[16];
    {
        const float* wrA = whh + ((size_t)g * HH + (size_t)(j0A + jj)) * HH;
        const float* wrB = whh + ((size_t)g * HH + (size_t)(j0B + jj)) * HH;
#pragma unroll
        for (int ks = 0; ks < 16; ++ks) {
            const float* pA = wrA + ks * 32 + ko;
            const float* pB = wrB + ks * 32 + ko;
            short8 tA, tB;
#pragma unroll
            for (int i = 0; i < 8; ++i) { tA[i] = f2bs(pA[i]); tB[i] = f2bs(pB[i]); }
            bfA[ks] = tA; bfB[ks] = tB;
        }
    }

    const int mC = l >> 1;
    const int jjA = (l & 1) * 2;

    float csA0, csA1, csB0, csB1;
    {
        const float* cpA = c0 + (size_t)dir * BH + (size_t)mC * HH + j0A + jjA;
        const float* cpB = c0 + (size_t)dir * BH + (size_t)mC * HH + j0B + jjA;
        csA0 = cpA[0]; csA1 = cpA[1];
        csB0 = cpB[0]; csB1 = cpB[1];
    }

    bf16* hsl = h_buf + (size_t)dl * 2 * BH;
    const unsigned* gxw = (const unsigned*)(gx + (size_t)dl * GX1);

    // ---- stage initial h (fp32 h0 -> bf16 LDS) ----
    for (int q = 0; q < 64; ++q) {
        const int f = q * 256 + tid;
        h_s[f >> 9][f & 511] = f2bf(h0[(size_t)dir * BH + f]);
    }
    __syncthreads();

    // first gx fetch: 4 gate-planar dwords per col-group
    unsigned gwA[4], gwB[4];
    {
        const int t0 = dir ? (TT - 1) : 0;
#pragma unroll
        for (int gg = 0; gg < 4; ++gg) {
            gwA[gg] = gxw[((size_t)(t0 * 4 + gg) * 128 + cgA) * 64 + l];
            gwB[gg] = gxw[((size_t)(t0 * 4 + gg) * 128 + cgB) * 64 + l];
        }
    }

#pragma unroll 1
    for (int s = 0; s < TT; ++s) {
        const int t_x = dir ? (TT - 1 - s) : s;

        float hvA0, hvA1, hvB0, hvB1;
        cell_step(h_s, bfA, ex[wv][0], gwA, nl, ko, l, mC, jjA, csA0, csA1, hvA0, hvA1);
        cell_step(h_s, bfB, ex[wv][1], gwB, nl, ko, l, mC, jjA, csB0, csB1, hvB0, hvB1);

        if (s < TT - 1) {
            // ---- publish h pairs (relaxed agent stores, write-through) ----
            {
                bf16 a0 = f2bf(hvA0), a1 = f2bf(hvA1);
                bf16 b0 = f2bf(hvB0), b1 = f2bf(hvB1);
                unsigned pkA = (unsigned)*(unsigned short*)&a0 |
                               ((unsigned)*(unsigned short*)&a1 << 16);
                unsigned pkB = (unsigned)*(unsigned short*)&b0 |
                               ((unsigned)*(unsigned short*)&b1 << 16);
                bf16* base = hsl + (size_t)((s + 1) & 1) * BH + (size_t)mC * HH;
                __hip_atomic_store((unsigned*)(base + j0A + jjA), pkA,
                                   __ATOMIC_RELAXED, __HIP_MEMORY_SCOPE_AGENT);
                __hip_atomic_store((unsigned*)(base + j0B + jjA), pkB,
                                   __ATOMIC_RELAXED, __HIP_MEMORY_SCOPE_AGENT);
            }
            asm volatile("s_waitcnt vmcnt(0)" ::: "memory");  // publish visible
            __syncthreads();                                   // whole WG published
            // ---- arrival: ONE fire-and-forget flag store (no RMW chain) ----
            if (tid == 0)
                __hip_atomic_store(barsd + wgl * 32, (unsigned)(s + 1),
                                   __ATOMIC_RELAXED, __HIP_MEMORY_SCOPE_AGENT);

            // ---- spin-window work: dout stores + next gx prefetch ----
            {
                float* db = dout + ((size_t)mC * TT + t_x) * (2 * HH) + (size_t)dir * HH;
                float2 ha; ha.x = hvA0; ha.y = hvA1;
                float2 hb; hb.x = hvB0; hb.y = hvB1;
                *(float2*)(db + j0A + jjA) = ha;
                *(float2*)(db + j0B + jjA) = hb;
            }
            const int t_n = dir ? (TT - 2 - s) : (s + 1);
            unsigned gwnA[4], gwnB[4];
#pragma unroll
            for (int gg = 0; gg < 4; ++gg) {
                gwnA[gg] = gxw[((size_t)(t_n * 4 + gg) * 128 + cgA) * 64 + l];
                gwnB[gg] = gxw[((size_t)(t_n * 4 + gg) * 128 + cgB) * 64 + l];
            }

            // ---- wave-0 spin: lane l polls flag[l&15], 16 lines in parallel ----
            if (wv == 0) {
                const unsigned tgt = (unsigned)(s + 1);
                while (true) {
                    unsigned v = __hip_atomic_load(barsd + (l & 15) * 32,
                                                   __ATOMIC_RELAXED, __HIP_MEMORY_SCOPE_AGENT);
                    if (__all(v >= tgt)) break;
                    __builtin_amdgcn_s_sleep(1);
                }
            }
            __syncthreads();

            // ---- restage h slot (s+1)&1: sc0 sc1 loads (L1/L2 bypass) ----
            {
                const u32x4* src = (const u32x4*)(hsl + (size_t)((s + 1) & 1) * BH);
                u32x4 vv[8];
#pragma unroll
                for (int q = 0; q < 8; ++q) {
                    const u32x4* p = src + (q * 256 + tid);
                    asm volatile("global_load_dwordx4 %0, %1, off sc0 sc1"
                                 : "=v"(vv[q]) : "v"(p));
                }
                asm volatile("s_waitcnt vmcnt(0)" ::: "memory");
#pragma unroll
                for (int q = 0; q < 8; ++q) {
                    const int e = (q * 256 + tid) * 8;
                    *(u32x4*)&h_s[e >> 9][e & 511] = vv[q];
                }
            }
            __syncthreads();
#pragma unroll
            for (int gg = 0; gg < 4; ++gg) { gwA[gg] = gwnA[gg]; gwB[gg] = gwnB[gg]; }
        } else {
            // ---- last step: dout + h_n/c_n for both col-groups ----
            const size_t hn_off = (size_t)BB * TT * 2 * HH;
            float* db = dout + ((size_t)mC * TT + t_x) * (2 * HH) + (size_t)dir * HH;
            float2 ha; ha.x = hvA0; ha.y = hvA1;
            float2 hb; hb.x = hvB0; hb.y = hvB1;
            *(float2*)(db + j0A + jjA) = ha;
            *(float2*)(db + j0B + jjA) = hb;
            float* hn = dout + hn_off + (size_t)dir * BH + (size_t)mC * HH;
            float* cn = dout + hn_off + 2 * (size_t)BH + (size_t)dir * BH + (size_t)mC * HH;
            *(float2*)(hn + j0A + jjA) = ha;
            *(float2*)(hn + j0B + jjA) = hb;
            float2 ca; ca.x = csA0; ca.y = csA1;
            float2 cb; cb.x = csB0; cb.y = csB1;
            *(float2*)(cn + j0A + jjA) = ca;
            *(float2*)(cn + j0B + jjA) = cb;
        }
    }
}

// ---------------------------------------------------------------------------
extern "C" void kernel_launch(void* const* d_in, const int* in_sizes, int n_in,
                              void* d_out, int out_size, void* d_ws, size_t ws_size,
                              hipStream_t stream)
{
    (void)in_sizes; (void)n_in; (void)out_size;
    const float* x     = (const float*)d_in[0];
    const float* h0    = (const float*)d_in[1];
    const float* c0    = (const float*)d_in[2];
    const float* wih_f = (const float*)d_in[3];
    const float* whh_f = (const float*)d_in[4];
    const float* bih_f = (const float*)d_in[5];
    const float* bhh_f = (const float*)d_in[6];
    const float* wih_r = (const float*)d_in[7];
    const float* whh_r = (const float*)d_in[8];
    const float* bih_r = (const float*)d_in[9];
    const float* bhh_r = (const float*)d_in[10];
    float* out = (float*)d_out;

    const size_t gx1 = GX1 * sizeof(bf16);                   // 64 MB per direction
    const size_t needA = 2 * gx1 + (size_t)4 * BH * sizeof(bf16) + 16384;
    char* ws = (char*)d_ws;

    if (ws_size >= needA) {
        // Plan A: both directions concurrently (32 4-wave WGs).
        bf16* gx = (bf16*)ws;
        bf16* h_buf = (bf16*)(ws + 2 * gx1);
        unsigned int* bars = (unsigned int*)(ws + 2 * gx1 + (size_t)4 * BH * sizeof(bf16));
        hipMemsetAsync(bars, 0, 8192, stream);
        dim3 g1(MM / 64, G4 / 128, 2);
        proj_mfma_kernel<<<g1, 256, 0, stream>>>(x, wih_f, wih_r, bih_f, bhh_f, bih_r, bhh_r, gx, 0);
        lstm_rec_kernel<<<dim3(2 * WGD), dim3(256), 0, stream>>>(
            gx, h0, c0, whh_f, whh_r, out, h_buf, bars, 0);
    } else {
        // Plan B: sequential per-direction, single 64 MB gx buffer reused.
        bf16* gx = (bf16*)ws;
        bf16* h_buf = (bf16*)(ws + gx1);
        unsigned int* bars = (unsigned int*)(ws + gx1 + (size_t)2 * BH * sizeof(bf16));
        for (int d = 0; d < 2; ++d) {
            hipMemsetAsync(bars, 0, 4096, stream);
            dim3 g1(MM / 64, G4 / 128, 1);
            proj_mfma_kernel<<<g1, 256, 0, stream>>>(x, wih_f, wih_r, bih_f, bhh_f, bih_r, bhh_r, gx, d);
            lstm_rec_kernel<<<dim3(WGD), dim3(256), 0, stream>>>(
                gx, h0, c0, whh_f, whh_r, out, h_buf, bars, d);
        }
    }
}

// Round 9
// 1881.197 us; speedup vs baseline: 1.3425x; 1.3425x over previous
//
#include <hip/hip_runtime.h>
#include <hip/hip_bf16.h>
#include <math.h>
#include <stdint.h>

#define BB 32
#define TT 512
#define II 512
#define HH 512
#define G4 (4 * HH)      // 2048
#define MM (TT * BB)     // 16384 rows of gx per direction
#define BH (BB * HH)     // 16384
#define WGD 32           // workgroups per direction in rec kernel (4 waves each)

typedef __hip_bfloat16 bf16;
typedef __attribute__((ext_vector_type(8))) short short8;   // 8 bf16 = 4 VGPRs
typedef __attribute__((ext_vector_type(4))) float f32x4;    // MFMA accumulator
typedef __attribute__((ext_vector_type(4))) unsigned u32x4; // for asm loads

__device__ __forceinline__ float bf2f(bf16 v) { return __bfloat162float(v); }
__device__ __forceinline__ bf16  f2bf(float v) { return __float2bfloat16(v); }
__device__ __forceinline__ short f2bs(float x) { bf16 v = f2bf(x); return *reinterpret_cast<short*>(&v); }
__device__ __forceinline__ float bs2f(short s) {
    unsigned u = ((unsigned)(unsigned short)s) << 16;
    return __uint_as_float(u);
}
__device__ __forceinline__ short8 pk8(float4 u, float4 v) {
    short8 t;
    t[0] = f2bs(u.x); t[1] = f2bs(u.y); t[2] = f2bs(u.z); t[3] = f2bs(u.w);
    t[4] = f2bs(v.x); t[5] = f2bs(v.y); t[6] = f2bs(v.z); t[7] = f2bs(v.w);
    return t;
}

// gx gate-planar swizzle: [dl][t][g][cg 0..127][b*4 + jj] bf16
#define GX1 ((size_t)TT * 4 * 128 * 128)   // elements per direction (= MM*G4)

// ---------------------------------------------------------------------------
// Phase 1: input projection GEMM via MFMA (bf16 in / fp32 acc). Unchanged.
// ---------------------------------------------------------------------------
__global__ __launch_bounds__(256) void proj_mfma_kernel(
    const float* __restrict__ x,
    const float* __restrict__ w_f, const float* __restrict__ w_r,
    const float* __restrict__ bi_f, const float* __restrict__ bh_f,
    const float* __restrict__ bi_r, const float* __restrict__ bh_r,
    bf16* __restrict__ gx, int dir0)
{
    const int dl = blockIdx.z, dir = dir0 + dl;
    const int m0 = blockIdx.x * 64;
    const int n0 = blockIdx.y * 128;
    const float* __restrict__ w  = dir ? w_r  : w_f;
    const float* __restrict__ bi = dir ? bi_r : bi_f;
    const float* __restrict__ bh = dir ? bh_r : bh_f;

    __shared__ __align__(16) char smem[17408];
    bf16 (*As)[40]  = (bf16(*)[40])smem;            // 64 x (32+8 pad)
    bf16 (*Bs)[40]  = (bf16(*)[40])(smem + 5120);   // 128 x (32+8 pad)
    bf16 (*Cs)[136] = (bf16(*)[136])smem;           // 64 x 136 (reuses smem)

    const int tid = threadIdx.x;
    const int wv = tid >> 6, l = tid & 63;
    const int nl = l & 15, ko = (l >> 4) * 8;

    const int a_r = tid >> 2, a_s = tid & 3;
    const float* a_src = x + ((size_t)((m0 + a_r) & 31) * TT + (size_t)((m0 + a_r) >> 5)) * II + a_s * 8;
    const int b_r = tid >> 1, b_h = tid & 1;
    const float* b_src = w + (size_t)(n0 + b_r) * II + b_h * 16;

    f32x4 acc[8];
#pragma unroll
    for (int j = 0; j < 8; ++j) acc[j] = (f32x4){0.f, 0.f, 0.f, 0.f};

    float bias[8];
#pragma unroll
    for (int j = 0; j < 8; ++j) {
        const int n = n0 + j * 16 + nl;
        bias[j] = bi[n] + bh[n];
    }

    for (int k0 = 0; k0 < II; k0 += 32) {
        const float4 av0 = *(const float4*)(a_src + k0);
        const float4 av1 = *(const float4*)(a_src + k0 + 4);
        const float4 bv0 = *(const float4*)(b_src + k0);
        const float4 bv1 = *(const float4*)(b_src + k0 + 4);
        const float4 bv2 = *(const float4*)(b_src + k0 + 8);
        const float4 bv3 = *(const float4*)(b_src + k0 + 12);
        __syncthreads();   // previous tile fully consumed
        *(short8*)&As[a_r][a_s * 8] = pk8(av0, av1);
        *(short8*)&Bs[b_r][b_h * 16]     = pk8(bv0, bv1);
        *(short8*)&Bs[b_r][b_h * 16 + 8] = pk8(bv2, bv3);
        __syncthreads();
        const short8 a = *(const short8*)&As[wv * 16 + nl][ko];
#pragma unroll
        for (int j = 0; j < 8; ++j) {
            const short8 b = *(const short8*)&Bs[j * 16 + nl][ko];
            acc[j] = __builtin_amdgcn_mfma_f32_16x16x32_bf16(a, b, acc[j], 0, 0, 0);
        }
    }

    __syncthreads();
    const int row0 = (l >> 4) * 4;
#pragma unroll
    for (int j = 0; j < 8; ++j)
#pragma unroll
        for (int r = 0; r < 4; ++r)
            Cs[wv * 16 + row0 + r][j * 16 + nl] = f2bf(acc[j][r] + bias[j]);
    __syncthreads();

    bf16* gxd = gx + (size_t)dl * GX1;
    const int g   = n0 >> 9;
    const int cgb = (n0 & 511) >> 2;
    const int t_base = blockIdx.x * 2;
#pragma unroll
    for (int i = 0; i < 4; ++i) {
        const int c = i * 256 + tid;
        const int tl = c >> 9, cgl = (c >> 4) & 31, u = c & 15;
        const int r0 = tl * 32 + 2 * u;
        const uint2 lo = *(const uint2*)&Cs[r0][cgl * 4];
        const uint2 hi = *(const uint2*)&Cs[r0 + 1][cgl * 4];
        uint4 ov; ov.x = lo.x; ov.y = lo.y; ov.z = hi.x; ov.w = hi.y;
        *(uint4*)(gxd + ((((size_t)(t_base + tl) * 4 + g) * 128 + cgb + cgl) * 128 + u * 8)) = ov;
    }
}

// ---------------------------------------------------------------------------
// Shared per-direction cell step: MFMA (h.W^T) + gate math.
// ---------------------------------------------------------------------------
__device__ __forceinline__ void cell_step(
    const bf16 (*__restrict__ h_s)[520], const short8* __restrict__ bfrag,
    float (*__restrict__ exw)[36],            // this wave's ex slice [16][36]
    const unsigned* __restrict__ gw,
    int nl, int ko, int l, int mC, int jjA,
    float& cs0, float& cs1, float& hv0, float& hv1)
{
    f32x4 acc0 = {0.f, 0.f, 0.f, 0.f};
    f32x4 acc1 = {0.f, 0.f, 0.f, 0.f};
#pragma unroll
    for (int half = 0; half < 2; ++half) {
        short8 a0[8], a1[8];
#pragma unroll
        for (int k = 0; k < 8; ++k) {
            const int ks = half * 8 + k;
            a0[k] = *(const short8*)&h_s[nl][ks * 32 + ko];
            a1[k] = *(const short8*)&h_s[nl + 16][ks * 32 + ko];
        }
#pragma unroll
        for (int k = 0; k < 8; ++k) {
            acc0 = __builtin_amdgcn_mfma_f32_16x16x32_bf16(a0[k], bfrag[half * 8 + k], acc0, 0, 0, 0);
            acc1 = __builtin_amdgcn_mfma_f32_16x16x32_bf16(a1[k], bfrag[half * 8 + k], acc1, 0, 0, 0);
        }
    }
    const int row0 = (l >> 4) * 4;
    *(f32x4*)&exw[nl][row0]      = acc0;
    *(f32x4*)&exw[nl][16 + row0] = acc1;

#pragma unroll
    for (int c = 0; c < 2; ++c) {
        const int jc = jjA + c;
        const int sh = 16 * c;
        float q0 = exw[0 * 4 + jc][mC] + bs2f((short)(gw[0] >> sh));
        float q1 = exw[1 * 4 + jc][mC] + bs2f((short)(gw[1] >> sh));
        float q2 = exw[2 * 4 + jc][mC] + bs2f((short)(gw[2] >> sh));
        float q3 = exw[3 * 4 + jc][mC] + bs2f((short)(gw[3] >> sh));
        q0 = fminf(fmaxf(q0, -30.f), 30.f);
        q1 = fminf(fmaxf(q1, -30.f), 30.f);
        q2 = fminf(fmaxf(q2, -30.f), 30.f);
        q3 = fminf(fmaxf(q3, -30.f), 30.f);
        const float ig = 1.f / (1.f + __expf(-q0));
        const float fg = 1.f / (1.f + __expf(-q1));
        const float te = __expf(2.f * q2);
        const float gg = (te - 1.f) / (te + 1.f);
        const float og = 1.f / (1.f + __expf(-q3));
        float cs = (c == 0) ? cs0 : cs1;
        cs = fg * cs + ig * gg;
        const float csc = fminf(fmaxf(cs, -15.f), 15.f);
        const float t2 = __expf(2.f * csc);
        const float th = (t2 - 1.f) / (t2 + 1.f);
        const float h = og * th;
        if (c == 0) { cs0 = cs; hv0 = h; } else { cs1 = cs; hv1 = h; }
    }
}

// ---------------------------------------------------------------------------
// Phase 2: MFMA recurrence — the empirically optimal configuration (round 6):
//  - 32 WGs/dir x 4 waves; each wave owns ONE col-group.
//  - arrival: per-WG padded flag word (32 flags x 128 B per dir) written with
//    one fire-and-forget relaxed agent STORE (no RMW serialization).
//  - wave 0 spins, lane l polling flag[l&31] (32 lines in parallel).
//  - publish -> vmcnt(0) -> syncthreads -> flag; dout store + gx prefetch in
//    the spin window; sc0sc1 restage bypassing L1/L2.
// Verified 1584 us rec / 3.09 us per step. Every structural variant tested
// (wider WGs, fewer WGs, fused dirs, tagged/NaN rings, all-thread polls)
// regressed; the remaining cost is the serial device-scope exchange chain.
// ---------------------------------------------------------------------------
__global__ __launch_bounds__(256, 1) void lstm_rec_kernel(
    const bf16* __restrict__ gx,
    const float* __restrict__ h0, const float* __restrict__ c0,
    const float* __restrict__ whh_f, const float* __restrict__ whh_r,
    float* __restrict__ dout,
    bf16* __restrict__ h_buf,          // [ndir][2 slots][BH]
    unsigned int* __restrict__ bars,   // [ndir][32 flags x 32 uints (128B)]
    int dir0)
{
    const int dl  = blockIdx.x >> 5;
    const int wgl = blockIdx.x & 31;
    const int dir = dir0 + dl;
    const int tid = threadIdx.x;
    const int wv  = tid >> 6;            // wave 0..3
    const int l   = tid & 63;            // lane
    const int cg  = wgl * 4 + wv;        // col-group 0..127
    const int j0  = cg * 4;
    const float* __restrict__ whh = dir ? whh_r : whh_f;
    unsigned int* barsd = bars + (size_t)dl * 1024;

    __shared__ __align__(16) bf16 h_s[32][520];   // staged h, +8 pad
    __shared__ __align__(16) float ex[4][16][36]; // per-wave gate exchange

    const int nl = l & 15;                // packed col index = gate*4 + jj
    const int g  = nl >> 2, jj = nl & 3;
    const int ko = (l >> 4) * 8;          // k-octet within a K=32 MFMA step

    // ---- B fragments (w_hh) resident in registers ----
    short8 bfrag[16];
    {
        const float* wr = whh + ((size_t)g * HH + (size_t)(j0 + jj)) * HH;
#pragma unroll
        for (int ks = 0; ks < 16; ++ks) {
            const float* p = wr + ks * 32 + ko;
            short8 t;
#pragma unroll
            for (int i = 0; i < 8; ++i) t[i] = f2bs(p[i]);
            bfrag[ks] = t;
        }
    }

    const int mC = l >> 1;
    const int jjA = (l & 1) * 2;

    float cs0, cs1;
    {
        const float* cp = c0 + (size_t)dir * BH + (size_t)mC * HH + j0 + jjA;
        cs0 = cp[0]; cs1 = cp[1];
    }

    bf16* hsl = h_buf + (size_t)dl * 2 * BH;
    const unsigned* gxw = (const unsigned*)(gx + (size_t)dl * GX1);

    // ---- stage initial h (fp32 h0 -> bf16 LDS) ----
    for (int q = 0; q < 64; ++q) {
        const int f = q * 256 + tid;
        h_s[f >> 9][f & 511] = f2bf(h0[(size_t)dir * BH + f]);
    }
    __syncthreads();

    // first gx fetch: 4 gate-planar dwords (2 cells each)
    unsigned gw[4];
    {
        const int t0 = dir ? (TT - 1) : 0;
#pragma unroll
        for (int gg = 0; gg < 4; ++gg)
            gw[gg] = gxw[((size_t)(t0 * 4 + gg) * 128 + cg) * 64 + l];
    }

#pragma unroll 1
    for (int s = 0; s < TT; ++s) {
        const int t_x = dir ? (TT - 1 - s) : s;

        float hv0, hv1;
        cell_step(h_s, bfrag, ex[wv], gw, nl, ko, l, mC, jjA, cs0, cs1, hv0, hv1);

        if (s < TT - 1) {
            // ---- publish h FIRST (relaxed agent store, write-through) ----
            {
                bf16 hb0 = f2bf(hv0), hb1 = f2bf(hv1);
                unsigned pk = (unsigned)*(unsigned short*)&hb0 |
                              ((unsigned)*(unsigned short*)&hb1 << 16);
                unsigned* hp = (unsigned*)(hsl + (size_t)((s + 1) & 1) * BH + (size_t)mC * HH + j0 + jjA);
                __hip_atomic_store(hp, pk, __ATOMIC_RELAXED, __HIP_MEMORY_SCOPE_AGENT);
            }
            asm volatile("s_waitcnt vmcnt(0)" ::: "memory");  // publish visible
            __syncthreads();                                   // whole WG published
            // ---- arrival: ONE fire-and-forget flag store (no RMW chain) ----
            if (tid == 0)
                __hip_atomic_store(barsd + wgl * 32, (unsigned)(s + 1),
                                   __ATOMIC_RELAXED, __HIP_MEMORY_SCOPE_AGENT);

            // ---- spin-window work: dout store + next gx prefetch ----
            {
                float2 ho; ho.x = hv0; ho.y = hv1;
                *(float2*)(dout + ((size_t)mC * TT + t_x) * (2 * HH) + (size_t)dir * HH + j0 + jjA) = ho;
            }
            const int t_n = dir ? (TT - 2 - s) : (s + 1);
            unsigned gwn[4];
#pragma unroll
            for (int gg = 0; gg < 4; ++gg)
                gwn[gg] = gxw[((size_t)(t_n * 4 + gg) * 128 + cg) * 64 + l];

            // ---- wave-0 spin: lane l polls flag[l&31], 32 lines in parallel ----
            if (wv == 0) {
                const unsigned tgt = (unsigned)(s + 1);
                while (true) {
                    unsigned v = __hip_atomic_load(barsd + (l & 31) * 32,
                                                   __ATOMIC_RELAXED, __HIP_MEMORY_SCOPE_AGENT);
                    if (__all(v >= tgt)) break;
                    __builtin_amdgcn_s_sleep(1);
                }
            }
            __syncthreads();

            // ---- restage h slot (s+1)&1: sc0 sc1 loads (L1/L2 bypass) ----
            {
                const u32x4* src = (const u32x4*)(hsl + (size_t)((s + 1) & 1) * BH);
                u32x4 vv[8];
#pragma unroll
                for (int q = 0; q < 8; ++q) {
                    const u32x4* p = src + (q * 256 + tid);
                    asm volatile("global_load_dwordx4 %0, %1, off sc0 sc1"
                                 : "=v"(vv[q]) : "v"(p));
                }
                asm volatile("s_waitcnt vmcnt(0)" ::: "memory");
#pragma unroll
                for (int q = 0; q < 8; ++q) {
                    const int e = (q * 256 + tid) * 8;
                    *(u32x4*)&h_s[e >> 9][e & 511] = vv[q];
                }
            }
            __syncthreads();
#pragma unroll
            for (int gg = 0; gg < 4; ++gg) gw[gg] = gwn[gg];
        } else {
            // ---- last step: dout + h_n/c_n ----
            float2 ho; ho.x = hv0; ho.y = hv1;
            *(float2*)(dout + ((size_t)mC * TT + t_x) * (2 * HH) + (size_t)dir * HH + j0 + jjA) = ho;
            const size_t hn_off = (size_t)BB * TT * 2 * HH;
            float2 co; co.x = cs0; co.y = cs1;
            *(float2*)(dout + hn_off + (size_t)dir * BH + (size_t)mC * HH + j0 + jjA) = ho;
            *(float2*)(dout + hn_off + 2 * (size_t)BH + (size_t)dir * BH + (size_t)mC * HH + j0 + jjA) = co;
        }
    }
}

// ---------------------------------------------------------------------------
extern "C" void kernel_launch(void* const* d_in, const int* in_sizes, int n_in,
                              void* d_out, int out_size, void* d_ws, size_t ws_size,
                              hipStream_t stream)
{
    (void)in_sizes; (void)n_in; (void)out_size;
    const float* x     = (const float*)d_in[0];
    const float* h0    = (const float*)d_in[1];
    const float* c0    = (const float*)d_in[2];
    const float* wih_f = (const float*)d_in[3];
    const float* whh_f = (const float*)d_in[4];
    const float* bih_f = (const float*)d_in[5];
    const float* bhh_f = (const float*)d_in[6];
    const float* wih_r = (const float*)d_in[7];
    const float* whh_r = (const float*)d_in[8];
    const float* bih_r = (const float*)d_in[9];
    const float* bhh_r = (const float*)d_in[10];
    float* out = (float*)d_out;

    const size_t gx1 = GX1 * sizeof(bf16);                   // 64 MB per direction
    const size_t needA = 2 * gx1 + (size_t)4 * BH * sizeof(bf16) + 16384;
    char* ws = (char*)d_ws;

    if (ws_size >= needA) {
        // Plan A: both directions concurrently (64 4-wave WGs).
        bf16* gx = (bf16*)ws;
        bf16* h_buf = (bf16*)(ws + 2 * gx1);
        unsigned int* bars = (unsigned int*)(ws + 2 * gx1 + (size_t)4 * BH * sizeof(bf16));
        hipMemsetAsync(bars, 0, 8192, stream);
        dim3 g1(MM / 64, G4 / 128, 2);
        proj_mfma_kernel<<<g1, 256, 0, stream>>>(x, wih_f, wih_r, bih_f, bhh_f, bih_r, bhh_r, gx, 0);
        lstm_rec_kernel<<<dim3(2 * WGD), dim3(256), 0, stream>>>(
            gx, h0, c0, whh_f, whh_r, out, h_buf, bars, 0);
    } else {
        // Plan B: sequential per-direction, single 64 MB gx buffer reused.
        bf16* gx = (bf16*)ws;
        bf16* h_buf = (bf16*)(ws + gx1);
        unsigned int* bars = (unsigned int*)(ws + gx1 + (size_t)2 * BH * sizeof(bf16));
        for (int d = 0; d < 2; ++d) {
            hipMemsetAsync(bars, 0, 4096, stream);
            dim3 g1(MM / 64, G4 / 128, 1);
            proj_mfma_kernel<<<g1, 256, 0, stream>>>(x, wih_f, wih_r, bih_f, bhh_f, bih_r, bhh_r, gx, d);
            lstm_rec_kernel<<<dim3(WGD), dim3(256), 0, stream>>>(
                gx, h0, c0, whh_f, whh_r, out, h_buf, bars, d);
        }
    }
}